// Round 3
// baseline (177.400 us; speedup 1.0000x reference)
//
#include <hip/hip_runtime.h>
#include <hip/hip_bf16.h>
#include <stdint.h>

typedef __bf16 bf16x8 __attribute__((ext_vector_type(8)));
typedef float f32x4 __attribute__((ext_vector_type(4)));

#define RATIO   128
#define HEADDIM 512
#define RD      64      // rope head dim
#define NCW     64      // compressed tokens per sequence
#define BATCH   2
#define SEQ     8192
#define DIM     4096

__device__ __forceinline__ void gload16(const void* g, void* l) {
  __builtin_amdgcn_global_load_lds(
      (__attribute__((address_space(1))) const void*)g,
      (__attribute__((address_space(3))) void*)l, 16, 0, 0);
}

__device__ __forceinline__ __bf16 cvt_bf16(float f) {
  __hip_bfloat16 h = __float2bfloat16(f);
  return *reinterpret_cast<__bf16*>(&h);
}

// ---------------- prep: f32 weights [4096][512] -> swizzled bf16 tiles ----------------
// wTs layout: [wsel 2][hb 4][k0t 64] tiles; tile = [row 128][slot 8] chunks of 8 bf16.
// chunk (row, slot) holds w[k0t*64 + (slot^(row&7))*8 .. +8][hb*128+row]  (k-major 8)
// so that a LINEAR gload_lds stage puts chunk (row,c16) at LDS byte row*128+((c16^(row&7))<<4).
__global__ __launch_bounds__(256) void prep_weights(
    const float* __restrict__ w0, const float* __restrict__ w1,
    __hip_bfloat16* __restrict__ wTs) {
  __shared__ float tile[64][132];
  const int wsel = blockIdx.z, hb = blockIdx.y, k0t = blockIdx.x;
  const float* in = wsel ? w1 : w0;
  const int t = threadIdx.x;
  const int h4 = (t & 31) * 4;
  #pragma unroll
  for (int p = 0; p < 8; ++p) {
    const int k = (t >> 5) + p * 8;
    const f32x4 v = *reinterpret_cast<const f32x4*>(
        in + (size_t)(k0t * 64 + k) * HEADDIM + hb * 128 + h4);
    tile[k][h4 + 0] = v[0]; tile[k][h4 + 1] = v[1];
    tile[k][h4 + 2] = v[2]; tile[k][h4 + 3] = v[3];
  }
  __syncthreads();
  const int row = t >> 1;
  __hip_bfloat16* outbase =
      wTs + (((size_t)(wsel * 4 + hb) * 64 + k0t) * 1024 + (size_t)row * 8) * 8;
  #pragma unroll
  for (int q = 0; q < 4; ++q) {
    const int slot = (t & 1) * 4 + q;
    const int kk = (slot ^ (row & 7)) * 8;
    bf16x8 c;
    #pragma unroll
    for (int j = 0; j < 8; ++j) c[j] = cvt_bf16(tile[kk + j][row]);
    *reinterpret_cast<bf16x8*>(outbase + slot * 8) = c;
  }
}

// swizzled fragment read: 8 bf16 at (row, 16B-chunk c16)
__device__ __forceinline__ bf16x8 ldfrag(const __hip_bfloat16* s, int row, int c16) {
  return *reinterpret_cast<const bf16x8*>(
      reinterpret_cast<const char*>(s) + row * 128 + ((c16 ^ (row & 7)) << 4));
}

// ---------------- fused GEMM (kv + gate) + softmax-pool ----------------
__global__ __launch_bounds__(256, 2) void gemm_pool_kernel(
    const float* __restrict__ x,
    const __hip_bfloat16* __restrict__ wTs,
    const float* __restrict__ ape,       // [128][512] f32
    float* __restrict__ comp) {          // [2][64][512] f32
  __shared__ __hip_bfloat16 sA [128 * 64];
  __shared__ __hip_bfloat16 sKV[128 * 64];
  __shared__ __hip_bfloat16 sSC[128 * 64];
  __shared__ float red[3][2][128];

  const int u    = blockIdx.x;
  const int xcd  = u & 7;
  const int slot = u >> 3;
  const int win  = xcd + 8 * (slot >> 2);  // 0..127; 4 hb-blocks of a window share an XCD
  const int hb   = slot & 3;
  const int b    = win >> 6;
  const int nc   = win & 63;

  const int tid  = threadIdx.x;
  const int lane = tid & 63;
  const int wid  = tid >> 6;
  const int wm   = wid >> 1, wn = wid & 1;

  const float* xw = x + ((size_t)b * SEQ + (size_t)nc * RATIO) * DIM;
  const __hip_bfloat16* kvTiles = wTs + ((size_t)(0 * 4 + hb) * 64) * 8192;
  const __hip_bfloat16* scTiles = wTs + ((size_t)(1 * 4 + hb) * 64) * 8192;

  f32x4 acc_kv[4][4], acc_sc[4][4];
  #pragma unroll
  for (int i = 0; i < 4; ++i)
    #pragma unroll
    for (int j = 0; j < 4; ++j) {
      acc_kv[i][j] = {0.f, 0.f, 0.f, 0.f};
      acc_sc[i][j] = {0.f, 0.f, 0.f, 0.f};
    }

  const int r0   = tid >> 2;          // 0..63 (A-stage row)
  const int cb   = (tid & 3) * 16;    // f32 col base
  const int c16b = (tid & 3) * 2;     // 16B-chunk base

  for (int k0t = 0; k0t < 64; ++k0t) {
    const int k0 = k0t * 64;
    __syncthreads();
    // ---- stage B (both weights) via linear gload_lds of pre-swizzled tiles ----
    #pragma unroll
    for (int i = 0; i < 4; ++i) {
      const int ch = wid * 256 + i * 64;   // chunk base (wave-uniform)
      gload16(kvTiles + ((size_t)k0t * 1024 + ch + lane) * 8,
              (char*)sKV + ch * 16);
      gload16(scTiles + ((size_t)k0t * 1024 + ch + lane) * 8,
              (char*)sSC + ch * 16);
    }
    // ---- stage A: f32 load -> bf16 -> swizzled ds_write ----
    #pragma unroll
    for (int half = 0; half < 2; ++half) {
      const int r = r0 + half * 64;
      const f32x4* src = reinterpret_cast<const f32x4*>(xw + (size_t)r * DIM + k0 + cb);
      f32x4 v0 = src[0], v1 = src[1], v2 = src[2], v3 = src[3];
      bf16x8 a0, a1;
      #pragma unroll
      for (int j = 0; j < 4; ++j) {
        a0[j] = cvt_bf16(v0[j]); a0[4 + j] = cvt_bf16(v1[j]);
        a1[j] = cvt_bf16(v2[j]); a1[4 + j] = cvt_bf16(v3[j]);
      }
      char* abase = (char*)sA + r * 128;
      *reinterpret_cast<bf16x8*>(abase + ((c16b ^ (r & 7)) << 4)) = a0;
      *reinterpret_cast<bf16x8*>(abase + (((c16b + 1) ^ (r & 7)) << 4)) = a1;
    }
    asm volatile("s_waitcnt vmcnt(0)" ::: "memory");
    __syncthreads();

    #pragma unroll
    for (int s = 0; s < 2; ++s) {
      const int c16 = s * 4 + (lane >> 4);
      bf16x8 af[4];
      #pragma unroll
      for (int mt = 0; mt < 4; ++mt)
        af[mt] = ldfrag(sA, wm * 64 + mt * 16 + (lane & 15), c16);
      #pragma unroll
      for (int nt = 0; nt < 4; ++nt) {
        const int brow = wn * 64 + nt * 16 + (lane & 15);
        const bf16x8 bkv = ldfrag(sKV, brow, c16);
        const bf16x8 bsc = ldfrag(sSC, brow, c16);
        #pragma unroll
        for (int mt = 0; mt < 4; ++mt) {
          acc_kv[mt][nt] = __builtin_amdgcn_mfma_f32_16x16x32_bf16(af[mt], bkv, acc_kv[mt][nt], 0, 0, 0);
          acc_sc[mt][nt] = __builtin_amdgcn_mfma_f32_16x16x32_bf16(af[mt], bsc, acc_sc[mt][nt], 0, 0, 0);
        }
      }
    }
  }

  // ---- epilogue: softmax over the 128 window rows, pooled sum ----
  const int cl = lane & 15;
  const int g4 = (lane >> 4) * 4;

  #pragma unroll
  for (int nt = 0; nt < 4; ++nt) {
    const int h = hb * 128 + wn * 64 + nt * 16 + cl;
    #pragma unroll
    for (int mt = 0; mt < 4; ++mt) {
      const int rbase = wm * 64 + mt * 16 + g4;
      #pragma unroll
      for (int r = 0; r < 4; ++r)
        acc_sc[mt][nt][r] += ape[(size_t)(rbase + r) * HEADDIM + h];
    }
  }

  float mx[4];
  #pragma unroll
  for (int nt = 0; nt < 4; ++nt) {
    float m = -3.0e38f;
    #pragma unroll
    for (int mt = 0; mt < 4; ++mt)
      #pragma unroll
      for (int r = 0; r < 4; ++r) m = fmaxf(m, acc_sc[mt][nt][r]);
    m = fmaxf(m, __shfl_xor(m, 16));
    m = fmaxf(m, __shfl_xor(m, 32));
    mx[nt] = m;
  }
  if (lane < 16) {
    #pragma unroll
    for (int nt = 0; nt < 4; ++nt)
      red[0][wm][wn * 64 + nt * 16 + lane] = mx[nt];
  }
  __syncthreads();
  #pragma unroll
  for (int nt = 0; nt < 4; ++nt) {
    const int idx = wn * 64 + nt * 16 + cl;
    mx[nt] = fmaxf(red[0][0][idx], red[0][1][idx]);
  }

  float den[4], num[4];
  #pragma unroll
  for (int nt = 0; nt < 4; ++nt) {
    float d = 0.f, n = 0.f;
    #pragma unroll
    for (int mt = 0; mt < 4; ++mt)
      #pragma unroll
      for (int r = 0; r < 4; ++r) {
        const float e = __expf(acc_sc[mt][nt][r] - mx[nt]);
        d += e;
        n += e * acc_kv[mt][nt][r];
      }
    d += __shfl_xor(d, 16); d += __shfl_xor(d, 32);
    n += __shfl_xor(n, 16); n += __shfl_xor(n, 32);
    den[nt] = d; num[nt] = n;
  }
  if (lane < 16) {
    #pragma unroll
    for (int nt = 0; nt < 4; ++nt) {
      const int idx = wn * 64 + nt * 16 + lane;
      red[1][wm][idx] = den[nt];
      red[2][wm][idx] = num[nt];
    }
  }
  __syncthreads();
  if (wm == 0 && lane < 16) {
    #pragma unroll
    for (int nt = 0; nt < 4; ++nt) {
      const int idx = wn * 64 + nt * 16 + lane;
      const float dt = red[1][0][idx] + red[1][1][idx];
      const float nu = red[2][0][idx] + red[2][1][idx];
      comp[((size_t)b * NCW + nc) * HEADDIM + hb * 128 + idx] = nu / dt;
    }
  }
}

// ---------------- RMSNorm + RoPE + scatter (all f32) ----------------
__global__ __launch_bounds__(64) void finalize_kernel(
    const float* __restrict__ comp,
    const float* __restrict__ nw,
    const float* __restrict__ cosg,
    const float* __restrict__ sing,
    const int* __restrict__ bo,
    float* __restrict__ out) {
  const int win = blockIdx.x;          // 0..127
  const int b = win >> 6, nc = win & 63;
  const int t = threadIdx.x;           // 64 threads, 8 ch each
  const float* cw = comp + (size_t)win * HEADDIM;

  float v[8];
  float ss = 0.f;
  #pragma unroll
  for (int j = 0; j < 8; ++j) { v[j] = cw[t * 8 + j]; ss += v[j] * v[j]; }
  #pragma unroll
  for (int o = 32; o; o >>= 1) ss += __shfl_xor(ss, o);
  const float scale = rsqrtf(ss / 512.0f + 1e-6f);

  float w[8];
  #pragma unroll
  for (int j = 0; j < 8; ++j) w[j] = v[j] * scale * nw[t * 8 + j];

  const int phys = bo[b];
  float* op = out + ((size_t)phys * NCW + nc) * HEADDIM + t * 8;
  if (t * 8 < HEADDIM - RD) {
    #pragma unroll
    for (int j = 0; j < 8; ++j) op[j] = w[j];
  } else {
    const int pos = nc * RATIO;
    #pragma unroll
    for (int j = 0; j < 8; j += 2) {
      const int i = (t * 8 + j - (HEADDIM - RD)) >> 1;  // 0..31
      const float co = cosg[(size_t)pos * 32 + i];
      const float si = sing[(size_t)pos * 32 + i];
      op[j]     = w[j] * co - w[j + 1] * si;
      op[j + 1] = w[j] * si + w[j + 1] * co;
    }
  }
}

extern "C" void kernel_launch(void* const* d_in, const int* in_sizes, int n_in,
                              void* d_out, int out_size, void* d_ws, size_t ws_size,
                              hipStream_t stream) {
  const float* x     = (const float*)d_in[0];
  const float* wkv   = (const float*)d_in[1];
  const float* wgate = (const float*)d_in[2];
  const float* ape   = (const float*)d_in[3];
  const float* nw    = (const float*)d_in[4];
  const float* cosg  = (const float*)d_in[5];
  const float* sing  = (const float*)d_in[6];
  const int*   bo    = (const int*)d_in[7];
  float* out = (float*)d_out;

  __hip_bfloat16* wTs = (__hip_bfloat16*)d_ws;                        // 8 MB swizzled tiles
  float* comp = (float*)((char*)d_ws + (size_t)2 * HEADDIM * DIM * sizeof(__hip_bfloat16)); // 256 KB

  (void)hipMemsetAsync(d_out, 0, (size_t)out_size * sizeof(float), stream);
  prep_weights<<<dim3(64, 4, 2), 256, 0, stream>>>(wkv, wgate, wTs);
  gemm_pool_kernel<<<dim3(512), 256, 0, stream>>>(x, wTs, ape, comp);
  finalize_kernel<<<dim3(128), 64, 0, stream>>>(comp, nw, cosg, sing, bo, out);
}